// Round 6
// baseline (156.729 us; speedup 1.0000x reference)
//
#include <hip/hip_runtime.h>
#include <math.h>

#define NN 4096
#define DD 512
#define MARGINF 1.0f
#define NCLS 64
#define MAXM 160
#define TRI (MAXM * (MAXM - 1) / 2)   // 12720
#define NBLK 2080                     // 64*65/2 triangular 64-tiles

typedef __attribute__((ext_vector_type(8))) short bf16x8;  // 8 bf16 (4 VGPRs)
typedef __attribute__((ext_vector_type(4))) float f32x4;   // 4 fp32 acc

// ws layout (float indices):
#define WS_SQ   0         // float[4096] ||x_i||^2
#define WS_NS   4096      // float[4096] neg_sum
#define WS_LOSS 8192      // float[1] sum hinge^2
#define WS_CNT  8256      // int[64] class counts
#define WS_RK   8320      // int[4096] rank within class
#define WS_MEM  12416     // int[64*160] class member lists
#define WS_XB   32768     // ushort[4096*512] bf16 X (4 MB)
#define WS_PD   1081344   // float[64*TRI] positive-pair distances

__device__ __forceinline__ unsigned short f2bf(float f) {
    unsigned u = __float_as_uint(f);
    u += 0x7fffu + ((u >> 16) & 1u);   // round-to-nearest-even
    return (unsigned short)(u >> 16);
}

// Row norms + bf16 conversion + zero-init. One wave per row.
__global__ __launch_bounds__(256) void prep_kernel(const float* __restrict__ X,
                                                   float* __restrict__ ws) {
    const int wv = threadIdx.x >> 6, lane = threadIdx.x & 63;
    const int row = blockIdx.x * 4 + wv;
    const float4* xr = (const float4*)(X + (size_t)row * DD);
    float4 a = xr[lane], b = xr[lane + 64];
    float s = a.x * a.x + a.y * a.y + a.z * a.z + a.w * a.w
            + b.x * b.x + b.y * b.y + b.z * b.z + b.w * b.w;
#pragma unroll
    for (int off = 32; off; off >>= 1) s += __shfl_down(s, off, 64);
    if (lane == 0) { ws[WS_SQ + row] = s; ws[WS_NS + row] = 0.0f; }
    ushort4 pa = {f2bf(a.x), f2bf(a.y), f2bf(a.z), f2bf(a.w)};
    ushort4 pb = {f2bf(b.x), f2bf(b.y), f2bf(b.z), f2bf(b.w)};
    ushort4* xb = (ushort4*)((unsigned short*)(ws + WS_XB) + (size_t)row * DD);
    xb[lane] = pa;
    xb[lane + 64] = pb;
    if (blockIdx.x == 0) {
        if (threadIdx.x < NCLS) ((int*)(ws + WS_CNT))[threadIdx.x] = 0;
        if (threadIdx.x == 0) ws[WS_LOSS] = 0.0f;
    }
}

__global__ __launch_bounds__(256) void class_build_kernel(const int* __restrict__ tgt,
                                                          float* __restrict__ ws) {
    const int t = blockIdx.x * 256 + threadIdx.x;
    const int c = tgt[t];
    int p = atomicAdd(&((int*)(ws + WS_CNT))[c], 1);
    ((int*)(ws + WS_RK))[t] = p;
    if (p < MAXM) ((int*)(ws + WS_MEM))[c * MAXM + p] = t;
}

// Gram via bf16 MFMA with DIRECT global->VGPR fragment loads: no LDS, no
// barriers, no vmcnt(0) drains. 64x64 tile per block (triangular grid,
// 2080 blocks), 4 waves each computing a 32x32 quadrant (2x2 MFMA).
// Fragment layout A[m=lane&15][k=q*8+j] maps to per-lane 16B loads at
// row (tile+u*16+m_), byte offset it*64 + q*16 -> folds into imm offset.
// 2-deep register pipeline hides L2 latency via vmcnt(N) scheduling.
__global__ __launch_bounds__(256, 4) void negsum_kernel(const int* __restrict__ tgt,
                                                        float* __restrict__ ws) {
    const int bidx = blockIdx.x;
    int bj = (int)((sqrtf(8.0f * (float)bidx + 1.0f) - 1.0f) * 0.5f);
    while (bj * (bj + 1) / 2 > bidx) --bj;
    while ((bj + 1) * (bj + 2) / 2 <= bidx) ++bj;
    const int bi = bidx - bj * (bj + 1) / 2;   // bi <= bj
    const int i0 = bi * 64, j0 = bj * 64;

    const int tid = threadIdx.x;
    const int w = tid >> 6, lane = tid & 63;
    const int m_ = lane & 15, q = lane >> 4;
    const int wr = (w & 1) * 32, wc = (w >> 1) * 32;
    const unsigned short* Xb = (const unsigned short*)(ws + WS_XB);

    // per-lane fragment base pointers (k-offset folded into load imm)
    const unsigned short* pA0 = Xb + (size_t)(i0 + wr + m_) * DD + q * 8;
    const unsigned short* pA1 = pA0 + (size_t)16 * DD;
    const unsigned short* pB0 = Xb + (size_t)(j0 + wc + m_) * DD + q * 8;
    const unsigned short* pB1 = pB0 + (size_t)16 * DD;

    f32x4 acc[2][2] = {};

    bf16x8 a0 = *(const bf16x8*)(pA0);
    bf16x8 a1 = *(const bf16x8*)(pA1);
    bf16x8 b0 = *(const bf16x8*)(pB0);
    bf16x8 b1 = *(const bf16x8*)(pB1);

#pragma unroll
    for (int it = 0; it < 16; ++it) {
        bf16x8 na0, na1, nb0, nb1;
        if (it < 15) {
            na0 = *(const bf16x8*)(pA0 + (it + 1) * 32);
            na1 = *(const bf16x8*)(pA1 + (it + 1) * 32);
            nb0 = *(const bf16x8*)(pB0 + (it + 1) * 32);
            nb1 = *(const bf16x8*)(pB1 + (it + 1) * 32);
        }
        acc[0][0] = __builtin_amdgcn_mfma_f32_16x16x32_bf16(a0, b0, acc[0][0], 0, 0, 0);
        acc[0][1] = __builtin_amdgcn_mfma_f32_16x16x32_bf16(a0, b1, acc[0][1], 0, 0, 0);
        acc[1][0] = __builtin_amdgcn_mfma_f32_16x16x32_bf16(a1, b0, acc[1][0], 0, 0, 0);
        acc[1][1] = __builtin_amdgcn_mfma_f32_16x16x32_bf16(a1, b1, acc[1][1], 0, 0, 0);
        a0 = na0; a1 = na1; b0 = nb0; b1 = nb1;
    }

    // epilogue: C/D map col=lane&15, row=(lane>>4)*4+reg
    const float* sq = ws + WS_SQ;
    float* ns = ws + WS_NS;
    const int* rk = (const int*)(ws + WS_RK);
    float* posd = ws + WS_PD;
    float sjv[2]; int tjv[2], jv[2];
#pragma unroll
    for (int v = 0; v < 2; ++v) {
        int j = j0 + wc + v * 16 + m_;
        jv[v] = j;
        sjv[v] = sq[j];
        tjv[v] = tgt[j];
    }
    float colp[2] = {0.0f, 0.0f};
#pragma unroll
    for (int u = 0; u < 2; ++u) {
#pragma unroll
        for (int r = 0; r < 4; ++r) {
            const int i = i0 + wr + u * 16 + q * 4 + r;
            const float si = sq[i];
            const int ti = tgt[i];
            float rp = 0.0f;
#pragma unroll
            for (int v = 0; v < 2; ++v) {
                float d2 = si + sjv[v] - 2.0f * acc[u][v][r];
                float dist = d2 > 0.0f ? sqrtf(d2) : 0.0f;
                if (tjv[v] != ti) {
                    float e = __expf(MARGINF - dist);
                    rp += e;
                    colp[v] += e;
                } else if (i < jv[v]) {
                    int ra = rk[i], rb = rk[jv[v]];
                    if (ra < MAXM && rb < MAXM) {
                        int hi = ra > rb ? ra : rb;
                        int lo = ra > rb ? rb : ra;
                        posd[ti * TRI + hi * (hi - 1) / 2 + lo] = dist;
                    }
                }
            }
            rp += __shfl_xor(rp, 1, 64);
            rp += __shfl_xor(rp, 2, 64);
            rp += __shfl_xor(rp, 4, 64);
            rp += __shfl_xor(rp, 8, 64);
            if (m_ == 0) atomicAdd(&ns[i], rp);
        }
    }
    if (bi != bj) {   // symmetric contribution: G[j][i] == G[i][j]
#pragma unroll
        for (int v = 0; v < 2; ++v) {
            float cp = colp[v];
            cp += __shfl_xor(cp, 16, 64);
            cp += __shfl_xor(cp, 32, 64);
            if (q == 0) atomicAdd(&ns[jv[v]], cp);
        }
    }
}

// Positive pairs from stored distances.
__global__ __launch_bounds__(256) void pair2_kernel(float* __restrict__ ws) {
    __shared__ float wsum[4];
    const int c = blockIdx.x;
    int mc = ((const int*)(ws + WS_CNT))[c];
    if (mc > MAXM) mc = MAXM;
    const int P = mc * (mc - 1) / 2;
    const int* mem = (const int*)(ws + WS_MEM) + c * MAXM;
    const float* pd = ws + WS_PD + c * TRI;
    const float* ns = ws + WS_NS;
    float lsum = 0.0f;
    for (int p = threadIdx.x; p < P; p += 256) {
        int b = (int)((1.0f + sqrtf(1.0f + 8.0f * (float)p)) * 0.5f);
        while (b * (b - 1) / 2 > p) --b;
        while ((b + 1) * b / 2 <= p) ++b;
        const int a = p - b * (b - 1) / 2;
        const float dist = pd[b * (b - 1) / 2 + a];
        const int i = mem[a], j = mem[b];
        float J = __logf(ns[i] + ns[j]) + dist;
        float h = fmaxf(J, 0.0f);
        lsum += h * h;
    }
#pragma unroll
    for (int off = 32; off; off >>= 1) lsum += __shfl_xor(lsum, off, 64);
    const int wv = threadIdx.x >> 6, lane = threadIdx.x & 63;
    if (lane == 0) wsum[wv] = lsum;
    __syncthreads();
    if (threadIdx.x == 0) {
        float s = wsum[0] + wsum[1] + wsum[2] + wsum[3];
        if (s != 0.0f) atomicAdd(&ws[WS_LOSS], s);
    }
}

__global__ void finalize_kernel(const float* __restrict__ ws, float* __restrict__ out) {
    const int t = threadIdx.x;
    int mcv = (t < NCLS) ? ((const int*)(ws + WS_CNT))[t] : 0;
    float lp = (float)(mcv * (mcv - 1));
#pragma unroll
    for (int off = 32; off; off >>= 1) lp += __shfl_down(lp, off, 64);
    if (t == 0) out[0] = ws[WS_LOSS] / lp;
}

extern "C" void kernel_launch(void* const* d_in, const int* in_sizes, int n_in,
                              void* d_out, int out_size, void* d_ws, size_t ws_size,
                              hipStream_t stream) {
    const float* X  = (const float*)d_in[0];
    const int*  tgt = (const int*)d_in[1];
    float* ws  = (float*)d_ws;
    float* out = (float*)d_out;

    hipLaunchKernelGGL(prep_kernel, dim3(NN / 4), dim3(256), 0, stream, X, ws);
    hipLaunchKernelGGL(class_build_kernel, dim3(NN / 256), dim3(256), 0, stream, tgt, ws);
    hipLaunchKernelGGL(negsum_kernel, dim3(NBLK), dim3(256), 0, stream, tgt, ws);
    hipLaunchKernelGGL(pair2_kernel, dim3(NCLS), dim3(256), 0, stream, ws);
    hipLaunchKernelGGL(finalize_kernel, dim3(1), dim3(64), 0, stream, ws, out);
}

// Round 7
// 122.567 us; speedup vs baseline: 1.2787x; 1.2787x over previous
//
#include <hip/hip_runtime.h>
#include <math.h>

#define NN 4096
#define DD 512
#define MARGINF 1.0f
#define NCLS 64
#define MAXM 160
#define TRI (MAXM * (MAXM - 1) / 2)   // 12720
#define NBLK 528                      // 32*33/2 triangular 128-tiles

typedef __attribute__((ext_vector_type(8))) short bf16x8;  // 8 bf16 (4 VGPRs)
typedef __attribute__((ext_vector_type(4))) float f32x4;   // 4 fp32 acc

// ws layout (float indices):
#define WS_SQ   0         // float[4096] ||x_i||^2
#define WS_NS   4096      // float[4096] neg_sum
#define WS_LOSS 8192      // float[1] sum hinge^2
#define WS_CNT  8256      // int[64] class counts
#define WS_RK   8320      // int[4096] rank within class
#define WS_MEM  12416     // int[64*160] class member lists
#define WS_XB   32768     // ushort[4096*512] bf16 X (4 MB)
#define WS_PD   1081344   // float[64*TRI] positive-pair distances

__device__ __forceinline__ unsigned short f2bf(float f) {
    unsigned u = __float_as_uint(f);
    u += 0x7fffu + ((u >> 16) & 1u);   // round-to-nearest-even
    return (unsigned short)(u >> 16);
}

// Row norms + bf16 conversion + zero-init. One wave per row.
__global__ __launch_bounds__(256) void prep_kernel(const float* __restrict__ X,
                                                   float* __restrict__ ws) {
    const int wv = threadIdx.x >> 6, lane = threadIdx.x & 63;
    const int row = blockIdx.x * 4 + wv;
    const float4* xr = (const float4*)(X + (size_t)row * DD);
    float4 a = xr[lane], b = xr[lane + 64];
    float s = a.x * a.x + a.y * a.y + a.z * a.z + a.w * a.w
            + b.x * b.x + b.y * b.y + b.z * b.z + b.w * b.w;
#pragma unroll
    for (int off = 32; off; off >>= 1) s += __shfl_down(s, off, 64);
    if (lane == 0) { ws[WS_SQ + row] = s; ws[WS_NS + row] = 0.0f; }
    ushort4 pa = {f2bf(a.x), f2bf(a.y), f2bf(a.z), f2bf(a.w)};
    ushort4 pb = {f2bf(b.x), f2bf(b.y), f2bf(b.z), f2bf(b.w)};
    ushort4* xb = (ushort4*)((unsigned short*)(ws + WS_XB) + (size_t)row * DD);
    xb[lane] = pa;
    xb[lane + 64] = pb;
    if (blockIdx.x == 0) {
        if (threadIdx.x < NCLS) ((int*)(ws + WS_CNT))[threadIdx.x] = 0;
        if (threadIdx.x == 0) ws[WS_LOSS] = 0.0f;
    }
}

__global__ __launch_bounds__(256) void class_build_kernel(const int* __restrict__ tgt,
                                                          float* __restrict__ ws) {
    const int t = blockIdx.x * 256 + threadIdx.x;
    const int c = tgt[t];
    int p = atomicAdd(&((int*)(ws + WS_CNT))[c], 1);
    ((int*)(ws + WS_RK))[t] = p;
    if (p < MAXM) ((int*)(ws + WS_MEM))[c * MAXM + p] = t;
}

// Gram via bf16 MFMA: 128x128 tile, BK=32, triangular grid (528 blocks).
// m93-style REGISTER-STAGED pipeline: global->VGPR prefetch of tile k+1
// issued before tile k's MFMA phase; ds_write at top of next iter. The
// pre-barrier wait is lgkmcnt (cheap), not a vmcnt(0) drain of in-flight
// global loads -- global latency is overlapped with compute.
__global__ __launch_bounds__(256, 3) void negsum_kernel(const int* __restrict__ tgt,
                                                        float* __restrict__ ws) {
    __shared__ unsigned short As[128 * 32];   // [row][k], 8 KB
    __shared__ unsigned short Bs[128 * 32];

    const int bidx = blockIdx.x;
    int bj = (int)((sqrtf(8.0f * (float)bidx + 1.0f) - 1.0f) * 0.5f);
    while (bj * (bj + 1) / 2 > bidx) --bj;
    while ((bj + 1) * (bj + 2) / 2 <= bidx) ++bj;
    const int bi = bidx - bj * (bj + 1) / 2;   // bi <= bj
    const int i0 = bi * 128, j0 = bj * 128;

    const int tid = threadIdx.x;
    const int w = tid >> 6, lane = tid & 63;
    const unsigned short* Xb = (const unsigned short*)(ws + WS_XB);

    // staging: thread tid covers (row = tid>>2, 16B chunk = tid&3) of rows
    // [0,64) and [64,128) of both tiles. LDS dst = tid*8 elems (linear,
    // conflict-free b128 writes).
    const int srow = tid >> 2, schk = tid & 3;
    const unsigned short* gA0 = Xb + (size_t)(i0 + srow) * DD + schk * 8;
    const unsigned short* gA1 = gA0 + (size_t)64 * DD;
    const unsigned short* gB0 = Xb + (size_t)(j0 + srow) * DD + schk * 8;
    const unsigned short* gB1 = gB0 + (size_t)64 * DD;

    const int m_ = lane & 15, q = lane >> 4;
    const int wr = (w & 1) * 64, wc = (w >> 1) * 64;

    f32x4 acc[4][4] = {};

    bf16x8 rA0 = *(const bf16x8*)gA0;
    bf16x8 rA1 = *(const bf16x8*)gA1;
    bf16x8 rB0 = *(const bf16x8*)gB0;
    bf16x8 rB1 = *(const bf16x8*)gB1;

    for (int it = 0; it < 16; ++it) {
        if (it) __syncthreads();               // prev readers done with LDS
        *(bf16x8*)(As + tid * 8) = rA0;
        *(bf16x8*)(As + 2048 + tid * 8) = rA1;
        *(bf16x8*)(Bs + tid * 8) = rB0;
        *(bf16x8*)(Bs + 2048 + tid * 8) = rB1;
        if (it < 15) {                         // prefetch k+1 (lands during MFMA)
            rA0 = *(const bf16x8*)(gA0 + (it + 1) * 32);
            rA1 = *(const bf16x8*)(gA1 + (it + 1) * 32);
            rB0 = *(const bf16x8*)(gB0 + (it + 1) * 32);
            rB1 = *(const bf16x8*)(gB1 + (it + 1) * 32);
        }
        __syncthreads();                       // ds_writes visible (lgkmcnt)
        bf16x8 af[4], bfr[4];
#pragma unroll
        for (int u = 0; u < 4; ++u)
            af[u] = *(const bf16x8*)(As + (wr + u * 16 + m_) * 32 + q * 8);
#pragma unroll
        for (int v = 0; v < 4; ++v)
            bfr[v] = *(const bf16x8*)(Bs + (wc + v * 16 + m_) * 32 + q * 8);
#pragma unroll
        for (int u = 0; u < 4; ++u)
#pragma unroll
            for (int v = 0; v < 4; ++v)
                acc[u][v] = __builtin_amdgcn_mfma_f32_16x16x32_bf16(
                    af[u], bfr[v], acc[u][v], 0, 0, 0);
    }

    // epilogue: C/D map col=lane&15, row=(lane>>4)*4+reg
    const float* sq = ws + WS_SQ;
    float* ns = ws + WS_NS;
    const int* rk = (const int*)(ws + WS_RK);
    float* posd = ws + WS_PD;
    float sjv[4]; int tjv[4], jv[4];
#pragma unroll
    for (int v = 0; v < 4; ++v) {
        int j = j0 + wc + v * 16 + m_;
        jv[v] = j;
        sjv[v] = sq[j];
        tjv[v] = tgt[j];
    }
    float colp[4] = {0.0f, 0.0f, 0.0f, 0.0f};
#pragma unroll
    for (int u = 0; u < 4; ++u) {
#pragma unroll
        for (int r = 0; r < 4; ++r) {
            const int i = i0 + wr + u * 16 + q * 4 + r;
            const float si = sq[i];
            const int ti = tgt[i];
            float rp = 0.0f;
#pragma unroll
            for (int v = 0; v < 4; ++v) {
                float d2 = si + sjv[v] - 2.0f * acc[u][v][r];
                float dist = d2 > 0.0f ? sqrtf(d2) : 0.0f;
                if (tjv[v] != ti) {
                    float e = __expf(MARGINF - dist);
                    rp += e;
                    colp[v] += e;
                } else if (i < jv[v]) {
                    int ra = rk[i], rb = rk[jv[v]];
                    if (ra < MAXM && rb < MAXM) {
                        int hi = ra > rb ? ra : rb;
                        int lo = ra > rb ? rb : ra;
                        posd[ti * TRI + hi * (hi - 1) / 2 + lo] = dist;
                    }
                }
            }
            rp += __shfl_xor(rp, 1, 64);
            rp += __shfl_xor(rp, 2, 64);
            rp += __shfl_xor(rp, 4, 64);
            rp += __shfl_xor(rp, 8, 64);
            if (m_ == 0) atomicAdd(&ns[i], rp);
        }
    }
    if (bi != bj) {   // symmetric contribution: G[j][i] == G[i][j]
#pragma unroll
        for (int v = 0; v < 4; ++v) {
            float cp = colp[v];
            cp += __shfl_xor(cp, 16, 64);
            cp += __shfl_xor(cp, 32, 64);
            if (q == 0) atomicAdd(&ns[jv[v]], cp);
        }
    }
}

// Positive pairs from stored distances.
__global__ __launch_bounds__(256) void pair2_kernel(float* __restrict__ ws) {
    __shared__ float wsum[4];
    const int c = blockIdx.x;
    int mc = ((const int*)(ws + WS_CNT))[c];
    if (mc > MAXM) mc = MAXM;
    const int P = mc * (mc - 1) / 2;
    const int* mem = (const int*)(ws + WS_MEM) + c * MAXM;
    const float* pd = ws + WS_PD + c * TRI;
    const float* ns = ws + WS_NS;
    float lsum = 0.0f;
    for (int p = threadIdx.x; p < P; p += 256) {
        int b = (int)((1.0f + sqrtf(1.0f + 8.0f * (float)p)) * 0.5f);
        while (b * (b - 1) / 2 > p) --b;
        while ((b + 1) * b / 2 <= p) ++b;
        const int a = p - b * (b - 1) / 2;
        const float dist = pd[b * (b - 1) / 2 + a];
        const int i = mem[a], j = mem[b];
        float J = __logf(ns[i] + ns[j]) + dist;
        float h = fmaxf(J, 0.0f);
        lsum += h * h;
    }
#pragma unroll
    for (int off = 32; off; off >>= 1) lsum += __shfl_xor(lsum, off, 64);
    const int wv = threadIdx.x >> 6, lane = threadIdx.x & 63;
    if (lane == 0) wsum[wv] = lsum;
    __syncthreads();
    if (threadIdx.x == 0) {
        float s = wsum[0] + wsum[1] + wsum[2] + wsum[3];
        if (s != 0.0f) atomicAdd(&ws[WS_LOSS], s);
    }
}

__global__ void finalize_kernel(const float* __restrict__ ws, float* __restrict__ out) {
    const int t = threadIdx.x;
    int mcv = (t < NCLS) ? ((const int*)(ws + WS_CNT))[t] : 0;
    float lp = (float)(mcv * (mcv - 1));
#pragma unroll
    for (int off = 32; off; off >>= 1) lp += __shfl_down(lp, off, 64);
    if (t == 0) out[0] = ws[WS_LOSS] / lp;
}

extern "C" void kernel_launch(void* const* d_in, const int* in_sizes, int n_in,
                              void* d_out, int out_size, void* d_ws, size_t ws_size,
                              hipStream_t stream) {
    const float* X  = (const float*)d_in[0];
    const int*  tgt = (const int*)d_in[1];
    float* ws  = (float*)d_ws;
    float* out = (float*)d_out;

    hipLaunchKernelGGL(prep_kernel, dim3(NN / 4), dim3(256), 0, stream, X, ws);
    hipLaunchKernelGGL(class_build_kernel, dim3(NN / 256), dim3(256), 0, stream, tgt, ws);
    hipLaunchKernelGGL(negsum_kernel, dim3(NBLK), dim3(256), 0, stream, tgt, ws);
    hipLaunchKernelGGL(pair2_kernel, dim3(NCLS), dim3(256), 0, stream, ws);
    hipLaunchKernelGGL(finalize_kernel, dim3(1), dim3(64), 0, stream, ws, out);
}